// Round 1
// baseline (943.866 us; speedup 1.0000x reference)
//
#include <hip/hip_runtime.h>
#include <hip/hip_bf16.h>

typedef __bf16 bf16;
typedef __bf16 bf16x8 __attribute__((ext_vector_type(8)));
typedef float f32x4 __attribute__((ext_vector_type(4)));

#define B_SZ 4
#define S_SZ 2048
#define DIN 4096
#define DOUT 4096
#define NAD 8
#define RNK 64
#define M_TOT (B_SZ * S_SZ)   // 8192
#define N1 (3 * NAD * RNK)    // 1536
#define K1 DIN                // 4096
#define K2 (NAD * RNK)        // 512

static __device__ __forceinline__ void async_cp16(const void* g, void* l) {
  __builtin_amdgcn_global_load_lds(
      (__attribute__((address_space(1))) void*)g,
      (__attribute__((address_space(3))) void*)l,
      16, 0, 0);
}

// ---------------------------------------------------------------- cast x -> bf16
__global__ __launch_bounds__(256) void cast_x_kernel(const float* __restrict__ x,
                                                     bf16* __restrict__ xb) {
  size_t i = ((size_t)blockIdx.x * 256 + threadIdx.x) * 8;
  float4 u = *(const float4*)(x + i);
  float4 v = *(const float4*)(x + i + 4);
  bf16x8 o;
  o[0] = (bf16)u.x; o[1] = (bf16)u.y; o[2] = (bf16)u.z; o[3] = (bf16)u.w;
  o[4] = (bf16)v.x; o[5] = (bf16)v.y; o[6] = (bf16)v.z; o[7] = (bf16)v.w;
  *(bf16x8*)(xb + i) = o;
}

// --------------------------------------------- pack A weights: [n][k][r] -> At[c][k]
// At row c = comp*512 + n*64 + r, length K1 (k-contiguous) == B^T layout for GEMM1.
__global__ __launch_bounds__(256) void pack_a_kernel(const float* __restrict__ qA,
                                                     const float* __restrict__ kA,
                                                     const float* __restrict__ vA,
                                                     bf16* __restrict__ At) {
  __shared__ bf16 t[64][65];
  const int ktile = blockIdx.x;  // 0..63 (K1/64)
  const int n = blockIdx.y;      // 0..7
  const int comp = blockIdx.z;   // 0..2
  const float* src = (comp == 0) ? qA : (comp == 1) ? kA : vA;
  src += (size_t)n * (DIN * RNK) + (size_t)ktile * 64 * RNK;
  const int tid = threadIdx.x;
  const int r = tid & 63, kq = tid >> 6;
#pragma unroll
  for (int i = 0; i < 16; ++i) {
    int kk = kq + i * 4;
    t[r][kk] = (bf16)src[(size_t)kk * RNK + r];  // coalesced read over r
  }
  __syncthreads();
  bf16* dst = At + (size_t)(comp * 512 + n * 64) * K1 + ktile * 64;
  const int kk2 = tid & 63, rq = tid >> 6;
#pragma unroll
  for (int i = 0; i < 16; ++i) {
    int rr = rq + i * 4;
    dst[(size_t)rr * K1 + kk2] = t[rr][kk2];  // coalesced write over k
  }
}

// --------------------------------------------- pack B weights: [k][o] -> Bt[c][o][k]
__global__ __launch_bounds__(256) void pack_b_kernel(const float* __restrict__ qB,
                                                     const float* __restrict__ kB,
                                                     const float* __restrict__ vB,
                                                     bf16* __restrict__ Bt) {
  __shared__ bf16 t[64][65];
  const int otile = blockIdx.x;  // 0..63 (DOUT/64)
  const int ktile = blockIdx.y;  // 0..7  (K2/64)
  const int comp = blockIdx.z;
  const float* src = (comp == 0) ? qB : (comp == 1) ? kB : vB;
  src += (size_t)ktile * 64 * DOUT + (size_t)otile * 64;
  const int tid = threadIdx.x;
  const int o = tid & 63, kq = tid >> 6;
#pragma unroll
  for (int i = 0; i < 16; ++i) {
    int kk = kq + i * 4;
    t[o][kk] = (bf16)src[(size_t)kk * DOUT + o];  // coalesced read over o
  }
  __syncthreads();
  bf16* dst = Bt + (size_t)comp * DOUT * K2 + (size_t)otile * 64 * K2 + ktile * 64;
  const int kk2 = tid & 63, oq = tid >> 6;
#pragma unroll
  for (int i = 0; i < 16; ++i) {
    int oo = oq + i * 4;
    dst[(size_t)oo * K2 + kk2] = t[oo][kk2];  // coalesced write over k
  }
}

// ----------------------------------------------------------- GEMM1: H = X @ Acat
// 128x128 tile, BK=32, 4 waves each computing 64x64 via 4x4 16x16x32 MFMA frags.
__global__ __launch_bounds__(256) void gemm1_kernel(
    const bf16* __restrict__ Xb,   // [8192][4096]
    const bf16* __restrict__ At,   // [1536][4096]  (row c, k-contiguous)
    bf16* __restrict__ H,          // [3][8192][512]
    const float* __restrict__ masks,     // [8][4]
    const float* __restrict__ scaling) { // [8]
  __shared__ bf16 As[128 * 32];
  __shared__ bf16 Bs[128 * 32];
  const int tm = blockIdx.x, tn = blockIdx.y;
  const int tid = threadIdx.x, wave = tid >> 6, lane = tid & 63;
  const int wm = wave >> 1, wn = wave & 1;
  const int lrow = lane & 15, quad = lane >> 4;
  const bf16* aP = Xb + (size_t)(tm * 128) * K1;
  const bf16* bP = At + (size_t)(tn * 128) * K1;
  const int srow = wave * 32 + (lane >> 2);   // staging row (wave covers 32 rows, 2 insts)
  const int schunk = (lane & 3) * 8;          // 8 bf16 = 16B per lane
  f32x4 acc[4][4] = {};
  for (int k0 = 0; k0 < K1; k0 += 32) {
    __syncthreads();
    async_cp16(aP + (size_t)srow * K1 + k0 + schunk,        As + (wave * 32) * 32);
    async_cp16(aP + (size_t)(srow + 16) * K1 + k0 + schunk, As + (wave * 32 + 16) * 32);
    async_cp16(bP + (size_t)srow * K1 + k0 + schunk,        Bs + (wave * 32) * 32);
    async_cp16(bP + (size_t)(srow + 16) * K1 + k0 + schunk, Bs + (wave * 32 + 16) * 32);
    __syncthreads();
    bf16x8 af[4], bfr[4];
#pragma unroll
    for (int i = 0; i < 4; ++i)
      af[i] = *(const bf16x8*)(As + (wm * 64 + i * 16 + lrow) * 32 + quad * 8);
#pragma unroll
    for (int j = 0; j < 4; ++j)
      bfr[j] = *(const bf16x8*)(Bs + (wn * 64 + j * 16 + lrow) * 32 + quad * 8);
#pragma unroll
    for (int i = 0; i < 4; ++i)
#pragma unroll
      for (int j = 0; j < 4; ++j)
        acc[i][j] = __builtin_amdgcn_mfma_f32_16x16x32_bf16(af[i], bfr[j], acc[i][j], 0, 0, 0);
  }
  // Epilogue: scale by coef[n][b] and store bf16 into H[comp][row][n*64+r].
  const int colbase = tn * 128 + wn * 64;     // 64-aligned -> single adapter per wave
  const int n_ad = (colbase >> 6) & 7;
  const int comp = colbase >> 9;
  const int b = tm >> 4;                      // row block of 128 within batch of 2048
  const float coef = scaling[n_ad] * masks[n_ad * 4 + b];
  bf16* hP = H + (size_t)comp * (M_TOT * K2);
#pragma unroll
  for (int i = 0; i < 4; ++i) {
#pragma unroll
    for (int j = 0; j < 4; ++j) {
      const int kc = (colbase + j * 16 + lrow) & 511;
#pragma unroll
      for (int e = 0; e < 4; ++e) {
        const int row = tm * 128 + wm * 64 + i * 16 + quad * 4 + e;
        hP[(size_t)row * K2 + kc] = (bf16)(acc[i][j][e] * coef);
      }
    }
  }
}

// ------------------------------------------------- GEMM2: out_c = H_c @ Bcat_c
__global__ __launch_bounds__(256) void gemm2_kernel(
    const bf16* __restrict__ H,    // [3][8192][512]
    const bf16* __restrict__ Bt,   // [3][4096][512]  (row o, k-contiguous)
    float* __restrict__ out) {     // [8192][12288]
  __shared__ bf16 As[128 * 32];
  __shared__ bf16 Bs[128 * 32];
  const int tm = blockIdx.x, tn = blockIdx.y, comp = blockIdx.z;
  const int tid = threadIdx.x, wave = tid >> 6, lane = tid & 63;
  const int wm = wave >> 1, wn = wave & 1;
  const int lrow = lane & 15, quad = lane >> 4;
  const bf16* aP = H + (size_t)comp * (M_TOT * K2) + (size_t)(tm * 128) * K2;
  const bf16* bP = Bt + (size_t)comp * (DOUT * K2) + (size_t)(tn * 128) * K2;
  const int srow = wave * 32 + (lane >> 2);
  const int schunk = (lane & 3) * 8;
  f32x4 acc[4][4] = {};
  for (int k0 = 0; k0 < K2; k0 += 32) {
    __syncthreads();
    async_cp16(aP + (size_t)srow * K2 + k0 + schunk,        As + (wave * 32) * 32);
    async_cp16(aP + (size_t)(srow + 16) * K2 + k0 + schunk, As + (wave * 32 + 16) * 32);
    async_cp16(bP + (size_t)srow * K2 + k0 + schunk,        Bs + (wave * 32) * 32);
    async_cp16(bP + (size_t)(srow + 16) * K2 + k0 + schunk, Bs + (wave * 32 + 16) * 32);
    __syncthreads();
    bf16x8 af[4], bfr[4];
#pragma unroll
    for (int i = 0; i < 4; ++i)
      af[i] = *(const bf16x8*)(As + (wm * 64 + i * 16 + lrow) * 32 + quad * 8);
#pragma unroll
    for (int j = 0; j < 4; ++j)
      bfr[j] = *(const bf16x8*)(Bs + (wn * 64 + j * 16 + lrow) * 32 + quad * 8);
#pragma unroll
    for (int i = 0; i < 4; ++i)
#pragma unroll
      for (int j = 0; j < 4; ++j)
        acc[i][j] = __builtin_amdgcn_mfma_f32_16x16x32_bf16(af[i], bfr[j], acc[i][j], 0, 0, 0);
  }
  float* oP = out + (size_t)comp * DOUT;
#pragma unroll
  for (int i = 0; i < 4; ++i) {
#pragma unroll
    for (int j = 0; j < 4; ++j) {
      const int col = tn * 128 + wn * 64 + j * 16 + lrow;
#pragma unroll
      for (int e = 0; e < 4; ++e) {
        const int row = tm * 128 + wm * 64 + i * 16 + quad * 4 + e;
        oP[(size_t)row * (3 * DOUT) + col] = acc[i][j][e];
      }
    }
  }
}

extern "C" void kernel_launch(void* const* d_in, const int* in_sizes, int n_in,
                              void* d_out, int out_size, void* d_ws, size_t ws_size,
                              hipStream_t stream) {
  (void)in_sizes; (void)n_in; (void)out_size; (void)ws_size;
  const float* x       = (const float*)d_in[0];
  // d_in[1] is the zeros "output" buffer -- unused.
  const float* masks   = (const float*)d_in[2];
  const float* scaling = (const float*)d_in[3];
  const float* qA      = (const float*)d_in[4];
  const float* qB      = (const float*)d_in[5];
  const float* kA      = (const float*)d_in[6];
  const float* kB      = (const float*)d_in[7];
  const float* vA      = (const float*)d_in[8];
  const float* vB      = (const float*)d_in[9];
  float* out = (float*)d_out;

  char* ws = (char*)d_ws;
  bf16* xb = (bf16*)ws;                                   // 8192*4096*2   = 64 MiB
  bf16* At = (bf16*)(ws + 67108864);                      // 1536*4096*2   = 12 MiB
  bf16* Bt = (bf16*)(ws + 67108864 + 12582912);           // 3*4096*512*2  = 12 MiB
  bf16* H  = (bf16*)(ws + 67108864 + 2 * 12582912);       // 3*8192*512*2  = 24 MiB

  cast_x_kernel<<<(M_TOT * (size_t)DIN) / 8 / 256, 256, 0, stream>>>(x, xb);
  pack_a_kernel<<<dim3(64, 8, 3), 256, 0, stream>>>(qA, kA, vA, At);
  pack_b_kernel<<<dim3(64, 8, 3), 256, 0, stream>>>(qB, kB, vB, Bt);
  gemm1_kernel<<<dim3(M_TOT / 128, N1 / 128), 256, 0, stream>>>(xb, At, H, masks, scaling);
  gemm2_kernel<<<dim3(M_TOT / 128, DOUT / 128, 3), 256, 0, stream>>>(H, Bt, out);
}